// Round 4
// baseline (1577.537 us; speedup 1.0000x reference)
//
#include <hip/hip_runtime.h>
#include <hip/hip_bf16.h>

#define DD 128
#define TM 64
#define LD 136   // padded LDS row stride (bf16 elems)

typedef short bf16x8 __attribute__((ext_vector_type(8)));
typedef float f32x4  __attribute__((ext_vector_type(4)));

__device__ __forceinline__ float bf2f(unsigned short u) {
  union { unsigned int i; float f; } x; x.i = ((unsigned int)u) << 16; return x.f;
}
__device__ __forceinline__ unsigned short f2bf(float f) {
  unsigned int u = __float_as_uint(f);
  u += 0x7FFFu + ((u >> 16) & 1u);   // RNE
  return (unsigned short)(u >> 16);
}
__device__ __forceinline__ unsigned int pack2(float lo, float hi) {
  return (unsigned int)f2bf(lo) | ((unsigned int)f2bf(hi) << 16);
}
// HW packed-bf16 atomic add (headers lack the overload; gfx950 has the instr)
__device__ __forceinline__ void atom_pk_bf16(unsigned short* p, unsigned int v) {
  asm volatile("global_atomic_pk_add_bf16 %0, %1, off" :: "v"(p), "v"(v) : "memory");
}
__device__ __forceinline__ bf16x8 ldw_f32(const float* p) {
  float4 a = *reinterpret_cast<const float4*>(p);
  float4 b = *reinterpret_cast<const float4*>(p + 4);
  bf16x8 r;
  r[0]=(short)f2bf(a.x); r[1]=(short)f2bf(a.y); r[2]=(short)f2bf(a.z); r[3]=(short)f2bf(a.w);
  r[4]=(short)f2bf(b.x); r[5]=(short)f2bf(b.y); r[6]=(short)f2bf(b.z); r[7]=(short)f2bf(b.w);
  return r;
}

// Classify feature dtype (1=fp32, 0=bf16) + zero the BN stat accumulators.
// fp32 N(0,1) words: |x| in (2^-30, 2^30). bf16-pair words as fp32: ~2^±120 or 0.
__global__ __launch_bounds__(64) void k_detect(const float* __restrict__ featw,
                                               int* __restrict__ flag,
                                               float* __restrict__ stats) {
  int t = threadIdx.x;
  int cnt = 0;
  for (int i = 0; i < 4; ++i) {
    float a = fabsf(featw[t + i * 64]);
    if (a > 9.3e-10f && a < 1.1e9f) cnt++;
  }
  for (int off = 32; off; off >>= 1) cnt += __shfl_xor(cnt, off);
  stats[t] = 0.f; stats[t + 64] = 0.f; stats[t + 128] = 0.f; stats[t + 192] = 0.f;
  if (t == 0) *flag = (cnt > 128) ? 1 : 0;
}

// out = feature (verbatim; out is the aggregation buffer). 1.6M threads.
__global__ __launch_bounds__(256) void k_copy(const void* __restrict__ feat,
                                              void* __restrict__ out,
                                              const int* __restrict__ flag) {
  long long t = (long long)blockIdx.x * 256 + threadIdx.x;
  if (*flag) {
    const float4* f = (const float4*)feat;
    float4* o = (float4*)out;
    o[t * 2]     = f[t * 2];
    o[t * 2 + 1] = f[t * 2 + 1];
  } else {
    ((uint4*)out)[t] = ((const uint4*)feat)[t];
  }
}

// out[dst] += feature[src]  (16 threads/edge, 8 cols each)
__global__ __launch_bounds__(256) void k_scatter(const void* __restrict__ feat,
                                                 const int* __restrict__ ei,
                                                 void* __restrict__ out, int ne,
                                                 const int* __restrict__ flag) {
  int t = blockIdx.x * 256 + threadIdx.x;
  int e = t >> 4;
  if (e >= ne) return;
  int c = (t & 15) << 3;
  int s = ei[e];
  int d = ei[ne + e];
  if (*flag) {
    const float* ff = (const float*)feat + (long long)s * DD + c;
    float4 a = *reinterpret_cast<const float4*>(ff);
    float4 b = *reinterpret_cast<const float4*>(ff + 4);
    float* p = (float*)out + (long long)d * DD + c;
    atomicAdd(p + 0, a.x); atomicAdd(p + 1, a.y);
    atomicAdd(p + 2, a.z); atomicAdd(p + 3, a.w);
    atomicAdd(p + 4, b.x); atomicAdd(p + 5, b.y);
    atomicAdd(p + 6, b.z); atomicAdd(p + 7, b.w);
  } else {
    const uint4 u = *reinterpret_cast<const uint4*>((const unsigned short*)feat + (long long)s * DD + c);
    unsigned short* p = (unsigned short*)out + (long long)d * DD + c;
    atom_pk_bf16(p + 0, u.x);
    atom_pk_bf16(p + 2, u.y);
    atom_pk_bf16(p + 4, u.z);
    atom_pk_bf16(p + 6, u.w);
  }
}

// Fused MLP (bf16 MFMA) + BN partial sums via fp32 atomics into stats[256].
// Block = 256 thr = 4 waves; wave owns 32 output cols; 64 rows per block.
__global__ __launch_bounds__(256) void k_mlp(
    const void* __restrict__ w1v, const void* __restrict__ b1v,
    const void* __restrict__ w2v, const void* __restrict__ b2v,
    void* __restrict__ out, float* __restrict__ stats, int nrows,
    const int* __restrict__ flag)
{
  __shared__ unsigned short ldsH[TM * LD];
  __shared__ unsigned short ldsH2[TM * LD];
  const bool fp = (*flag != 0);
  const int tid  = threadIdx.x;
  const int wave = tid >> 6, lane = tid & 63;
  const int q = lane >> 4, l16 = lane & 15;
  const int row0 = blockIdx.x * TM;
  const int col0 = wave * 32;

  // Weight B-frags (lane: n=lane&15, k=quad*8+j; B[k][n]=w[n][k]) + biases.
  bf16x8 bw1[2][4], bw2[2][4];
  float bias1[2], bias2[2];
  for (int n = 0; n < 2; ++n) {
    int jc = col0 + n * 16 + l16;
    if (fp) {
      bias1[n] = ((const float*)b1v)[jc];
      bias2[n] = ((const float*)b2v)[jc];
      for (int kk = 0; kk < 4; ++kk) {
        bw1[n][kk] = ldw_f32((const float*)w1v + jc * DD + kk * 32 + q * 8);
        bw2[n][kk] = ldw_f32((const float*)w2v + jc * DD + kk * 32 + q * 8);
      }
    } else {
      bias1[n] = bf2f(((const unsigned short*)b1v)[jc]);
      bias2[n] = bf2f(((const unsigned short*)b2v)[jc]);
      for (int kk = 0; kk < 4; ++kk) {
        bw1[n][kk] = *reinterpret_cast<const bf16x8*>((const unsigned short*)w1v + jc * DD + kk * 32 + q * 8);
        bw2[n][kk] = *reinterpret_cast<const bf16x8*>((const unsigned short*)w2v + jc * DD + kk * 32 + q * 8);
      }
    }
  }

  // Stage h tile from out into LDS (convert to bf16 if fp32).
  for (int it = 0; it < 4; ++it) {
    int idx = it * 2048 + tid * 8;
    int r = idx >> 7, c = idx & 127;
    uint4 u = make_uint4(0u, 0u, 0u, 0u);
    if (row0 + r < nrows) {
      if (fp) {
        const float* pf = (const float*)out + (long long)(row0 + r) * DD + c;
        float4 a = *reinterpret_cast<const float4*>(pf);
        float4 b = *reinterpret_cast<const float4*>(pf + 4);
        u.x = pack2(a.x, a.y); u.y = pack2(a.z, a.w);
        u.z = pack2(b.x, b.y); u.w = pack2(b.z, b.w);
      } else {
        u = *reinterpret_cast<const uint4*>((const unsigned short*)out + (long long)(row0 + r) * DD + c);
      }
    }
    *reinterpret_cast<uint4*>(&ldsH[r * LD + c]) = u;
  }
  __syncthreads();

  f32x4 acc[4][2];
  const f32x4 zero = {0.f, 0.f, 0.f, 0.f};
  for (int m = 0; m < 4; ++m) for (int n = 0; n < 2; ++n) acc[m][n] = zero;

  // GEMM1 (A: m=lane&15, k=quad*8+j)
  for (int kk = 0; kk < 4; ++kk) {
    bf16x8 aF[4];
    for (int m = 0; m < 4; ++m)
      aF[m] = *reinterpret_cast<const bf16x8*>(&ldsH[(m * 16 + l16) * LD + kk * 32 + q * 8]);
    for (int m = 0; m < 4; ++m)
      for (int n = 0; n < 2; ++n)
        acc[m][n] = __builtin_amdgcn_mfma_f32_16x16x32_bf16(aF[m], bw1[n][kk], acc[m][n], 0, 0, 0);
  }

  // h2 = relu(acc + b1) -> LDS (C/D: col=lane&15, row=quad*4+reg)
  for (int m = 0; m < 4; ++m)
    for (int n = 0; n < 2; ++n)
      for (int r = 0; r < 4; ++r) {
        float v = fmaxf(acc[m][n][r] + bias1[n], 0.f);
        ldsH2[(m * 16 + q * 4 + r) * LD + (col0 + n * 16 + l16)] = f2bf(v);
      }
  __syncthreads();

  for (int m = 0; m < 4; ++m) for (int n = 0; n < 2; ++n) acc[m][n] = zero;

  // GEMM2
  for (int kk = 0; kk < 4; ++kk) {
    bf16x8 aF[4];
    for (int m = 0; m < 4; ++m)
      aF[m] = *reinterpret_cast<const bf16x8*>(&ldsH2[(m * 16 + l16) * LD + kk * 32 + q * 8]);
    for (int m = 0; m < 4; ++m)
      for (int n = 0; n < 2; ++n)
        acc[m][n] = __builtin_amdgcn_mfma_f32_16x16x32_bf16(aF[m], bw2[n][kk], acc[m][n], 0, 0, 0);
  }

  // Final relu, store pre-BN h, accumulate BN partials.
  float s[2] = {0.f, 0.f}, s2[2] = {0.f, 0.f};
  for (int m = 0; m < 4; ++m)
    for (int n = 0; n < 2; ++n) {
      int col = col0 + n * 16 + l16;
      for (int r = 0; r < 4; ++r) {
        int row = row0 + m * 16 + q * 4 + r;
        float v = fmaxf(acc[m][n][r] + bias2[n], 0.f);
        if (row < nrows) {
          if (fp) ((float*)out)[(long long)row * DD + col] = v;
          else    ((unsigned short*)out)[(long long)row * DD + col] = f2bf(v);
          s[n]  += v;
          s2[n] += v * v;
        }
      }
    }
  for (int off = 16; off < 64; off <<= 1)
    for (int n = 0; n < 2; ++n) {
      s[n]  += __shfl_xor(s[n], off);
      s2[n] += __shfl_xor(s2[n], off);
    }
  if (q == 0)
    for (int n = 0; n < 2; ++n) {
      int col = col0 + n * 16 + l16;
      atomicAdd(&stats[col],       s[n]);
      atomicAdd(&stats[128 + col], s2[n]);
    }
}

// stats -> scale/shift
__global__ __launch_bounds__(128) void k_stats(const float* __restrict__ stats,
                                               const void* __restrict__ gamma,
                                               const void* __restrict__ beta,
                                               float* __restrict__ scsh, int nrows,
                                               const int* __restrict__ flag) {
  int t = threadIdx.x;
  float sum = stats[t], sq = stats[128 + t];
  float mean = sum / (float)nrows;
  float var  = fmaxf(sq / (float)nrows - mean * mean, 0.f);
  float inv  = rsqrtf(var + 1e-5f);
  float g, bt;
  if (*flag) { g = ((const float*)gamma)[t]; bt = ((const float*)beta)[t]; }
  else       { g = bf2f(((const unsigned short*)gamma)[t]); bt = bf2f(((const unsigned short*)beta)[t]); }
  float sc = g * inv;
  scsh[t]       = sc;
  scsh[128 + t] = bt - mean * sc;
}

// In-place BN apply on out. 1.6M threads, 8 elems each.
__global__ __launch_bounds__(256) void k_bn(void* __restrict__ out,
                                            const float* __restrict__ scsh,
                                            long long total8,
                                            const int* __restrict__ flag) {
  long long t = (long long)blockIdx.x * 256 + threadIdx.x;
  if (t >= total8) return;
  int c0 = (int)((t * 8) & 127);
  float4 sa = *reinterpret_cast<const float4*>(scsh + c0);
  float4 sb = *reinterpret_cast<const float4*>(scsh + c0 + 4);
  float4 ha = *reinterpret_cast<const float4*>(scsh + 128 + c0);
  float4 hb = *reinterpret_cast<const float4*>(scsh + 132 + c0);
  if (*flag) {
    float* of = (float*)out + t * 8;
    float4 a = *reinterpret_cast<float4*>(of);
    float4 b = *reinterpret_cast<float4*>(of + 4);
    a.x = a.x * sa.x + ha.x; a.y = a.y * sa.y + ha.y;
    a.z = a.z * sa.z + ha.z; a.w = a.w * sa.w + ha.w;
    b.x = b.x * sb.x + hb.x; b.y = b.y * sb.y + hb.y;
    b.z = b.z * sb.z + hb.z; b.w = b.w * sb.w + hb.w;
    *reinterpret_cast<float4*>(of)     = a;
    *reinterpret_cast<float4*>(of + 4) = b;
  } else {
    unsigned short* ob = (unsigned short*)out + t * 8;
    uint4 u = *reinterpret_cast<uint4*>(ob);
    float v0 = __uint_as_float(u.x << 16)          * sa.x + ha.x;
    float v1 = __uint_as_float(u.x & 0xFFFF0000u)  * sa.y + ha.y;
    float v2 = __uint_as_float(u.y << 16)          * sa.z + ha.z;
    float v3 = __uint_as_float(u.y & 0xFFFF0000u)  * sa.w + ha.w;
    float v4 = __uint_as_float(u.z << 16)          * sb.x + hb.x;
    float v5 = __uint_as_float(u.z & 0xFFFF0000u)  * sb.y + hb.y;
    float v6 = __uint_as_float(u.w << 16)          * sb.z + hb.z;
    float v7 = __uint_as_float(u.w & 0xFFFF0000u)  * sb.w + hb.w;
    u.x = pack2(v0, v1); u.y = pack2(v2, v3);
    u.z = pack2(v4, v5); u.w = pack2(v6, v7);
    *reinterpret_cast<uint4*>(ob) = u;
  }
}

extern "C" void kernel_launch(void* const* d_in, const int* in_sizes, int n_in,
                              void* d_out, int out_size, void* d_ws, size_t ws_size,
                              hipStream_t stream) {
  const void* feat  = d_in[0];
  const int*  eidx  = (const int*)d_in[1];
  const void* w1    = d_in[2];
  const void* b1    = d_in[3];
  const void* w2    = d_in[4];
  const void* b2    = d_in[5];
  const void* gamma = d_in[6];
  const void* beta  = d_in[7];

  const int nrows = in_sizes[0] / DD;       // 100000
  const int ne    = in_sizes[1] / 2;        // 400000
  const int nblk  = (nrows + TM - 1) / TM;  // 1563

  int*   flag  = (int*)d_ws;                 // [0]
  float* stats = (float*)d_ws + 64;          // 256 floats (sum | sumsq)
  float* scsh  = (float*)d_ws + 64 + 256;    // 256 floats (scale | shift)
  // total ws usage: 2304 bytes

  const long long total8 = (long long)nrows * DD / 8;   // 1.6M

  k_detect <<<1,                            64, 0, stream>>>((const float*)feat, flag, stats);
  k_copy   <<<(int)((total8 + 255) / 256), 256, 0, stream>>>(feat, d_out, flag);
  k_scatter<<<(ne * 16 + 255) / 256,       256, 0, stream>>>(feat, eidx, d_out, ne, flag);
  k_mlp    <<<nblk,                        256, 0, stream>>>(w1, b1, w2, b2, d_out, stats, nrows, flag);
  k_stats  <<<1,                           128, 0, stream>>>(stats, gamma, beta, scsh, nrows, flag);
  k_bn     <<<(int)((total8 + 255) / 256), 256, 0, stream>>>(d_out, scsh, total8, flag);
}

// Round 5
// 525.843 us; speedup vs baseline: 3.0000x; 3.0000x over previous
//
#include <hip/hip_runtime.h>
#include <hip/hip_bf16.h>

#define DD 128
#define TM 64
#define LD 136   // padded LDS row stride (bf16 elems)

typedef short bf16x8 __attribute__((ext_vector_type(8)));
typedef float f32x4  __attribute__((ext_vector_type(4)));

__device__ __forceinline__ unsigned short f2bf(float f) {
  unsigned int u = __float_as_uint(f);
  u += 0x7FFFu + ((u >> 16) & 1u);   // RNE
  return (unsigned short)(u >> 16);
}
__device__ __forceinline__ unsigned int pack2(float lo, float hi) {
  return (unsigned int)f2bf(lo) | ((unsigned int)f2bf(hi) << 16);
}

// cnt[dst]++ per edge (int atomics on 400 KB — L2-resident, fast)
__global__ __launch_bounds__(256) void k_hist(const int* __restrict__ ei, int* __restrict__ cnt,
                                              int ne) {
  int e = blockIdx.x * 256 + threadIdx.x;
  if (e < ne) atomicAdd(&cnt[ei[ne + e]], 1);
}

// Exclusive scan of cnt[0..n) -> ofs[0..n], plus cursor copy cur = ofs.
__global__ __launch_bounds__(1024) void k_scan(const int* __restrict__ cnt,
                                               int* __restrict__ ofs, int* __restrict__ cur,
                                               int n) {
  __shared__ int partial[1024];
  int t = threadIdx.x;
  int chunk = (n + 1023) >> 10;
  int lo = t * chunk, hi = min(n, lo + chunk);
  int s = 0;
  for (int i = lo; i < hi; ++i) s += cnt[i];
  partial[t] = s;
  __syncthreads();
  for (int off = 1; off < 1024; off <<= 1) {
    int v = (t >= off) ? partial[t - off] : 0;
    __syncthreads();
    partial[t] += v;
    __syncthreads();
  }
  int run = (t == 0) ? 0 : partial[t - 1];
  for (int i = lo; i < hi; ++i) {
    int c = cnt[i];
    ofs[i] = run; cur[i] = run;
    run += c;
  }
  if (t == 1023) ofs[n] = run;
}

// csr[pos] = src, pos = cur[dst]++
__global__ __launch_bounds__(256) void k_fill(const int* __restrict__ ei, int* __restrict__ cur,
                                              int* __restrict__ csr, int ne) {
  int e = blockIdx.x * 256 + threadIdx.x;
  if (e >= ne) return;
  int pos = atomicAdd(&cur[ei[ne + e]], 1);
  csr[pos] = ei[e];
}

// Fused: gather-aggregate h = x + sum(neighbors), 2-layer MLP via bf16 MFMA,
// write pre-BN result (fp32) to out, accumulate BN stats.
// Block = 256 thr = 4 waves; wave owns 32 output cols; 64 rows per block.
__global__ __launch_bounds__(256) void k_mlp(
    const float* __restrict__ feat, const int* __restrict__ ofs, const int* __restrict__ csr,
    const float* __restrict__ w1, const float* __restrict__ b1,
    const float* __restrict__ w2, const float* __restrict__ b2,
    float* __restrict__ out, float* __restrict__ stats, int nrows)
{
  __shared__ unsigned short ldsH[TM * LD];
  __shared__ unsigned short ldsH2[TM * LD];
  const int tid  = threadIdx.x;
  const int wave = tid >> 6, lane = tid & 63;
  const int q = lane >> 4, l16 = lane & 15;
  const int row0 = blockIdx.x * TM;
  const int col0 = wave * 32;

  // Weight B-frags (lane: n=lane&15, k=quad*8+j; B[k][n]=w[n][k]) + biases.
  bf16x8 bw1[2][4], bw2[2][4];
  float bias1[2], bias2[2];
  for (int n = 0; n < 2; ++n) {
    int jc = col0 + n * 16 + l16;
    bias1[n] = b1[jc];
    bias2[n] = b2[jc];
    for (int kk = 0; kk < 4; ++kk) {
      const float* p1 = w1 + jc * DD + kk * 32 + q * 8;
      const float* p2 = w2 + jc * DD + kk * 32 + q * 8;
      for (int j = 0; j < 8; ++j) {
        bw1[n][kk][j] = (short)f2bf(p1[j]);
        bw2[n][kk][j] = (short)f2bf(p2[j]);
      }
    }
  }

  // Stage h tile: h[row][c..c+7] = feat[row] + sum_{s in csr[ofs[row]:ofs[row+1])} feat[s]
  // 16 threads per row (8 cols each) -> neighbor row reads are 512B contiguous per group.
  for (int it = 0; it < 4; ++it) {
    int idx = it * 2048 + tid * 8;
    int r = idx >> 7, c = idx & 127;
    int row = row0 + r;
    uint4 u = make_uint4(0u, 0u, 0u, 0u);
    if (row < nrows) {
      const float* fr = feat + (long long)row * DD + c;
      float4 a = *reinterpret_cast<const float4*>(fr);
      float4 b = *reinterpret_cast<const float4*>(fr + 4);
      int o0 = ofs[row], o1 = ofs[row + 1];
      for (int j = o0; j < o1; ++j) {
        const float* fs = feat + (long long)csr[j] * DD + c;
        float4 x = *reinterpret_cast<const float4*>(fs);
        float4 y = *reinterpret_cast<const float4*>(fs + 4);
        a.x += x.x; a.y += x.y; a.z += x.z; a.w += x.w;
        b.x += y.x; b.y += y.y; b.z += y.z; b.w += y.w;
      }
      u.x = pack2(a.x, a.y); u.y = pack2(a.z, a.w);
      u.z = pack2(b.x, b.y); u.w = pack2(b.z, b.w);
    }
    *reinterpret_cast<uint4*>(&ldsH[r * LD + c]) = u;
  }
  __syncthreads();

  f32x4 acc[4][2];
  const f32x4 zero = {0.f, 0.f, 0.f, 0.f};
  for (int m = 0; m < 4; ++m) for (int n = 0; n < 2; ++n) acc[m][n] = zero;

  // GEMM1 (A: m=lane&15, k=quad*8+j)
  for (int kk = 0; kk < 4; ++kk) {
    bf16x8 aF[4];
    for (int m = 0; m < 4; ++m)
      aF[m] = *reinterpret_cast<const bf16x8*>(&ldsH[(m * 16 + l16) * LD + kk * 32 + q * 8]);
    for (int m = 0; m < 4; ++m)
      for (int n = 0; n < 2; ++n)
        acc[m][n] = __builtin_amdgcn_mfma_f32_16x16x32_bf16(aF[m], bw1[n][kk], acc[m][n], 0, 0, 0);
  }

  // h2 = relu(acc + b1) -> LDS (C/D: col=lane&15, row=quad*4+reg)
  for (int m = 0; m < 4; ++m)
    for (int n = 0; n < 2; ++n)
      for (int r = 0; r < 4; ++r) {
        float v = fmaxf(acc[m][n][r] + bias1[n], 0.f);
        ldsH2[(m * 16 + q * 4 + r) * LD + (col0 + n * 16 + l16)] = f2bf(v);
      }
  __syncthreads();

  for (int m = 0; m < 4; ++m) for (int n = 0; n < 2; ++n) acc[m][n] = zero;

  // GEMM2
  for (int kk = 0; kk < 4; ++kk) {
    bf16x8 aF[4];
    for (int m = 0; m < 4; ++m)
      aF[m] = *reinterpret_cast<const bf16x8*>(&ldsH2[(m * 16 + l16) * LD + kk * 32 + q * 8]);
    for (int m = 0; m < 4; ++m)
      for (int n = 0; n < 2; ++n)
        acc[m][n] = __builtin_amdgcn_mfma_f32_16x16x32_bf16(aF[m], bw2[n][kk], acc[m][n], 0, 0, 0);
  }

  // Final relu, store pre-BN h (fp32), accumulate BN stats.
  float s[2] = {0.f, 0.f}, s2[2] = {0.f, 0.f};
  for (int m = 0; m < 4; ++m)
    for (int n = 0; n < 2; ++n) {
      int col = col0 + n * 16 + l16;
      for (int r = 0; r < 4; ++r) {
        int row = row0 + m * 16 + q * 4 + r;
        float v = fmaxf(acc[m][n][r] + bias2[n], 0.f);
        if (row < nrows) {
          out[(long long)row * DD + col] = v;
          s[n]  += v;
          s2[n] += v * v;
        }
      }
    }
  for (int off = 16; off < 64; off <<= 1)
    for (int n = 0; n < 2; ++n) {
      s[n]  += __shfl_xor(s[n], off);
      s2[n] += __shfl_xor(s2[n], off);
    }
  if (q == 0)
    for (int n = 0; n < 2; ++n) {
      int col = col0 + n * 16 + l16;
      atomicAdd(&stats[col],       s[n]);
      atomicAdd(&stats[128 + col], s2[n]);
    }
}

// stats -> scale/shift
__global__ __launch_bounds__(128) void k_stats(const float* __restrict__ stats,
                                               const float* __restrict__ gamma,
                                               const float* __restrict__ beta,
                                               float* __restrict__ scsh, int nrows) {
  int t = threadIdx.x;
  float mean = stats[t] / (float)nrows;
  float var  = fmaxf(stats[128 + t] / (float)nrows - mean * mean, 0.f);
  float inv  = rsqrtf(var + 1e-5f);
  float sc   = gamma[t] * inv;
  scsh[t]       = sc;
  scsh[128 + t] = beta[t] - mean * sc;
}

// In-place BN apply on out (fp32). One thread per 8 elems.
__global__ __launch_bounds__(256) void k_bn(float* __restrict__ out,
                                            const float* __restrict__ scsh,
                                            long long total8) {
  long long t = (long long)blockIdx.x * 256 + threadIdx.x;
  if (t >= total8) return;
  int c0 = (int)((t * 8) & 127);
  float4 sa = *reinterpret_cast<const float4*>(scsh + c0);
  float4 sb = *reinterpret_cast<const float4*>(scsh + c0 + 4);
  float4 ha = *reinterpret_cast<const float4*>(scsh + 128 + c0);
  float4 hb = *reinterpret_cast<const float4*>(scsh + 132 + c0);
  float* of = out + t * 8;
  float4 a = *reinterpret_cast<float4*>(of);
  float4 b = *reinterpret_cast<float4*>(of + 4);
  a.x = a.x * sa.x + ha.x; a.y = a.y * sa.y + ha.y;
  a.z = a.z * sa.z + ha.z; a.w = a.w * sa.w + ha.w;
  b.x = b.x * sb.x + hb.x; b.y = b.y * sb.y + hb.y;
  b.z = b.z * sb.z + hb.z; b.w = b.w * sb.w + hb.w;
  *reinterpret_cast<float4*>(of)     = a;
  *reinterpret_cast<float4*>(of + 4) = b;
}

extern "C" void kernel_launch(void* const* d_in, const int* in_sizes, int n_in,
                              void* d_out, int out_size, void* d_ws, size_t ws_size,
                              hipStream_t stream) {
  const float* feat  = (const float*)d_in[0];
  const int*   eidx  = (const int*)d_in[1];
  const float* w1    = (const float*)d_in[2];
  const float* b1    = (const float*)d_in[3];
  const float* w2    = (const float*)d_in[4];
  const float* b2    = (const float*)d_in[5];
  const float* gamma = (const float*)d_in[6];
  const float* beta  = (const float*)d_in[7];
  float* out = (float*)d_out;

  const int nrows = in_sizes[0] / DD;       // 100000
  const int ne    = in_sizes[1] / 2;        // 400000
  const int nblk  = (nrows + TM - 1) / TM;  // 1563

  // ws layout (floats/ints, 4B each):
  //  scsh[256] | ofs[nrows+1] | cur[nrows] | csr[ne] | stats[256] | cnt[nrows]
  float* scsh  = (float*)d_ws;
  int*   ofs   = (int*)d_ws + 256;
  int*   cur   = ofs + (nrows + 1);
  int*   csr   = cur + nrows;
  float* stats = (float*)(csr + ne);
  int*   cnt   = (int*)(stats + 256);
  // total: ~2.8 MB

  // zero stats + cnt in one contiguous memset (graph-capture-safe)
  hipMemsetAsync(stats, 0, (256 + (size_t)nrows) * sizeof(float), stream);

  const long long total8 = (long long)nrows * DD / 8;   // 1.6M

  k_hist <<<(ne + 255) / 256,             256, 0, stream>>>(eidx, cnt, ne);
  k_scan <<<1,                           1024, 0, stream>>>(cnt, ofs, cur, nrows);
  k_fill <<<(ne + 255) / 256,             256, 0, stream>>>(eidx, cur, csr, ne);
  k_mlp  <<<nblk,                         256, 0, stream>>>(feat, ofs, csr, w1, b1, w2, b2, out, stats, nrows);
  k_stats<<<1,                            128, 0, stream>>>(stats, gamma, beta, scsh, nrows);
  k_bn   <<<(int)((total8 + 255) / 256),  256, 0, stream>>>(out, scsh, total8);
}

// Round 6
// 304.755 us; speedup vs baseline: 5.1764x; 1.7255x over previous
//
#include <hip/hip_runtime.h>
#include <hip/hip_bf16.h>

#define DD 128
#define TM 64
#define LD 136   // padded LDS row stride (bf16 elems)
#define SB 128   // scan blocks

typedef short bf16x8 __attribute__((ext_vector_type(8)));
typedef float f32x4  __attribute__((ext_vector_type(4)));

__device__ __forceinline__ unsigned short f2bf(float f) {
  unsigned int u = __float_as_uint(f);
  u += 0x7FFFu + ((u >> 16) & 1u);   // RNE
  return (unsigned short)(u >> 16);
}
__device__ __forceinline__ unsigned int pack2(float lo, float hi) {
  return (unsigned int)f2bf(lo) | ((unsigned int)f2bf(hi) << 16);
}

// cnt[dst]++ per edge (int atomics on 400 KB — L2-resident)
__global__ __launch_bounds__(256) void k_hist(const int* __restrict__ ei, int* __restrict__ cnt,
                                              int ne) {
  int e = blockIdx.x * 256 + threadIdx.x;
  if (e < ne) atomicAdd(&cnt[ei[ne + e]], 1);
}

// ---- 3-stage parallel exclusive scan of cnt[0..n) -> ofs[0..n], cur = ofs ----
__global__ __launch_bounds__(256) void k_scan1(const int* __restrict__ cnt,
                                               int* __restrict__ bsum, int n) {
  __shared__ int red[256];
  int b = blockIdx.x, t = threadIdx.x;
  int chunk = (n + SB - 1) / SB;
  int lo = b * chunk, hi = min(n, lo + chunk);
  int s = 0;
  for (int i = lo + t; i < hi; i += 256) s += cnt[i];
  red[t] = s;
  __syncthreads();
  for (int off = 128; off; off >>= 1) {
    if (t < off) red[t] += red[t + off];
    __syncthreads();
  }
  if (t == 0) bsum[b] = red[0];
}

__global__ __launch_bounds__(SB) void k_scan2(const int* __restrict__ bsum,
                                              int* __restrict__ bofs,
                                              int* __restrict__ ofs, int n) {
  __shared__ int tmp[SB];
  int t = threadIdx.x;
  int mine = bsum[t];
  tmp[t] = mine;
  __syncthreads();
  for (int off = 1; off < SB; off <<= 1) {
    int v = (t >= off) ? tmp[t - off] : 0;
    __syncthreads();
    tmp[t] += v;
    __syncthreads();
  }
  bofs[t] = tmp[t] - mine;            // exclusive
  if (t == SB - 1) ofs[n] = tmp[t];   // total
}

__global__ __launch_bounds__(256) void k_scan3(const int* __restrict__ cnt,
                                               const int* __restrict__ bofs,
                                               int* __restrict__ ofs, int* __restrict__ cur,
                                               int n) {
  __shared__ int red[256];
  int b = blockIdx.x, t = threadIdx.x;
  int chunk  = (n + SB - 1) / SB;
  int tchunk = (chunk + 255) / 256;
  int blo = b * chunk, bhi = min(n, blo + chunk);
  int lo = blo + t * tchunk, hi = min(bhi, lo + tchunk);
  int s = 0;
  for (int i = lo; i < hi; ++i) s += cnt[i];
  int mine = s;
  red[t] = s;
  __syncthreads();
  for (int off = 1; off < 256; off <<= 1) {
    int v = (t >= off) ? red[t - off] : 0;
    __syncthreads();
    red[t] += v;
    __syncthreads();
  }
  int run = bofs[b] + red[t] - mine;  // exclusive prefix for this thread's chunk
  for (int i = lo; i < hi; ++i) {
    int c = cnt[i];
    ofs[i] = run; cur[i] = run;
    run += c;
  }
}

// csr[pos] = src, pos = cur[dst]++
__global__ __launch_bounds__(256) void k_fill(const int* __restrict__ ei, int* __restrict__ cur,
                                              int* __restrict__ csr, int ne) {
  int e = blockIdx.x * 256 + threadIdx.x;
  if (e >= ne) return;
  int pos = atomicAdd(&cur[ei[ne + e]], 1);
  csr[pos] = ei[e];
}

// Fused: gather-aggregate h = x + sum(neighbors), 2-layer MLP via bf16 MFMA,
// write pre-BN result (fp32) to out, accumulate BN stats.
// Block = 256 thr = 4 waves; wave owns 32 output cols; 64 rows per block.
__global__ __launch_bounds__(256) void k_mlp(
    const float* __restrict__ feat, const int* __restrict__ ofs, const int* __restrict__ csr,
    const float* __restrict__ w1, const float* __restrict__ b1,
    const float* __restrict__ w2, const float* __restrict__ b2,
    float* __restrict__ out, float* __restrict__ stats, int nrows)
{
  __shared__ unsigned short ldsH[TM * LD];
  __shared__ unsigned short ldsH2[TM * LD];
  const int tid  = threadIdx.x;
  const int wave = tid >> 6, lane = tid & 63;
  const int q = lane >> 4, l16 = lane & 15;
  const int row0 = blockIdx.x * TM;
  const int col0 = wave * 32;

  // Weight B-frags (lane: n=lane&15, k=quad*8+j; B[k][n]=w[n][k]) + biases.
  bf16x8 bw1[2][4], bw2[2][4];
  float bias1[2], bias2[2];
  for (int n = 0; n < 2; ++n) {
    int jc = col0 + n * 16 + l16;
    bias1[n] = b1[jc];
    bias2[n] = b2[jc];
    for (int kk = 0; kk < 4; ++kk) {
      const float* p1 = w1 + jc * DD + kk * 32 + q * 8;
      const float* p2 = w2 + jc * DD + kk * 32 + q * 8;
      for (int j = 0; j < 8; ++j) {
        bw1[n][kk][j] = (short)f2bf(p1[j]);
        bw2[n][kk][j] = (short)f2bf(p2[j]);
      }
    }
  }

  // Stage h tile: 16 threads/row (8 cols each); neighbor reads 512B contiguous/group.
  for (int it = 0; it < 4; ++it) {
    int idx = it * 2048 + tid * 8;
    int r = idx >> 7, c = idx & 127;
    int row = row0 + r;
    uint4 u = make_uint4(0u, 0u, 0u, 0u);
    if (row < nrows) {
      const float* fr = feat + (long long)row * DD + c;
      float4 a = *reinterpret_cast<const float4*>(fr);
      float4 b = *reinterpret_cast<const float4*>(fr + 4);
      int o0 = ofs[row], o1 = ofs[row + 1];
      for (int j = o0; j < o1; ++j) {
        const float* fs = feat + (long long)csr[j] * DD + c;
        float4 x = *reinterpret_cast<const float4*>(fs);
        float4 y = *reinterpret_cast<const float4*>(fs + 4);
        a.x += x.x; a.y += x.y; a.z += x.z; a.w += x.w;
        b.x += y.x; b.y += y.y; b.z += y.z; b.w += y.w;
      }
      u.x = pack2(a.x, a.y); u.y = pack2(a.z, a.w);
      u.z = pack2(b.x, b.y); u.w = pack2(b.z, b.w);
    }
    *reinterpret_cast<uint4*>(&ldsH[r * LD + c]) = u;
  }
  __syncthreads();

  f32x4 acc[4][2];
  const f32x4 zero = {0.f, 0.f, 0.f, 0.f};
  for (int m = 0; m < 4; ++m) for (int n = 0; n < 2; ++n) acc[m][n] = zero;

  // GEMM1 (A: m=lane&15, k=quad*8+j)
  for (int kk = 0; kk < 4; ++kk) {
    bf16x8 aF[4];
    for (int m = 0; m < 4; ++m)
      aF[m] = *reinterpret_cast<const bf16x8*>(&ldsH[(m * 16 + l16) * LD + kk * 32 + q * 8]);
    for (int m = 0; m < 4; ++m)
      for (int n = 0; n < 2; ++n)
        acc[m][n] = __builtin_amdgcn_mfma_f32_16x16x32_bf16(aF[m], bw1[n][kk], acc[m][n], 0, 0, 0);
  }

  // h2 = relu(acc + b1) -> LDS (C/D: col=lane&15, row=quad*4+reg)
  for (int m = 0; m < 4; ++m)
    for (int n = 0; n < 2; ++n)
      for (int r = 0; r < 4; ++r) {
        float v = fmaxf(acc[m][n][r] + bias1[n], 0.f);
        ldsH2[(m * 16 + q * 4 + r) * LD + (col0 + n * 16 + l16)] = f2bf(v);
      }
  __syncthreads();

  for (int m = 0; m < 4; ++m) for (int n = 0; n < 2; ++n) acc[m][n] = zero;

  // GEMM2
  for (int kk = 0; kk < 4; ++kk) {
    bf16x8 aF[4];
    for (int m = 0; m < 4; ++m)
      aF[m] = *reinterpret_cast<const bf16x8*>(&ldsH2[(m * 16 + l16) * LD + kk * 32 + q * 8]);
    for (int m = 0; m < 4; ++m)
      for (int n = 0; n < 2; ++n)
        acc[m][n] = __builtin_amdgcn_mfma_f32_16x16x32_bf16(aF[m], bw2[n][kk], acc[m][n], 0, 0, 0);
  }

  // Final relu, store pre-BN h (fp32), accumulate BN stats.
  float s[2] = {0.f, 0.f}, s2[2] = {0.f, 0.f};
  for (int m = 0; m < 4; ++m)
    for (int n = 0; n < 2; ++n) {
      int col = col0 + n * 16 + l16;
      for (int r = 0; r < 4; ++r) {
        int row = row0 + m * 16 + q * 4 + r;
        float v = fmaxf(acc[m][n][r] + bias2[n], 0.f);
        if (row < nrows) {
          out[(long long)row * DD + col] = v;
          s[n]  += v;
          s2[n] += v * v;
        }
      }
    }
  for (int off = 16; off < 64; off <<= 1)
    for (int n = 0; n < 2; ++n) {
      s[n]  += __shfl_xor(s[n], off);
      s2[n] += __shfl_xor(s2[n], off);
    }
  if (q == 0)
    for (int n = 0; n < 2; ++n) {
      int col = col0 + n * 16 + l16;
      atomicAdd(&stats[col],       s[n]);
      atomicAdd(&stats[128 + col], s2[n]);
    }
}

// stats -> scale/shift
__global__ __launch_bounds__(128) void k_stats(const float* __restrict__ stats,
                                               const float* __restrict__ gamma,
                                               const float* __restrict__ beta,
                                               float* __restrict__ scsh, int nrows) {
  int t = threadIdx.x;
  float mean = stats[t] / (float)nrows;
  float var  = fmaxf(stats[128 + t] / (float)nrows - mean * mean, 0.f);
  float inv  = rsqrtf(var + 1e-5f);
  float sc   = gamma[t] * inv;
  scsh[t]       = sc;
  scsh[128 + t] = beta[t] - mean * sc;
}

// In-place BN apply on out (fp32). One thread per 8 elems.
__global__ __launch_bounds__(256) void k_bn(float* __restrict__ out,
                                            const float* __restrict__ scsh,
                                            long long total8) {
  long long t = (long long)blockIdx.x * 256 + threadIdx.x;
  if (t >= total8) return;
  int c0 = (int)((t * 8) & 127);
  float4 sa = *reinterpret_cast<const float4*>(scsh + c0);
  float4 sb = *reinterpret_cast<const float4*>(scsh + c0 + 4);
  float4 ha = *reinterpret_cast<const float4*>(scsh + 128 + c0);
  float4 hb = *reinterpret_cast<const float4*>(scsh + 132 + c0);
  float* of = out + t * 8;
  float4 a = *reinterpret_cast<float4*>(of);
  float4 b = *reinterpret_cast<float4*>(of + 4);
  a.x = a.x * sa.x + ha.x; a.y = a.y * sa.y + ha.y;
  a.z = a.z * sa.z + ha.z; a.w = a.w * sa.w + ha.w;
  b.x = b.x * sb.x + hb.x; b.y = b.y * sb.y + hb.y;
  b.z = b.z * sb.z + hb.z; b.w = b.w * sb.w + hb.w;
  *reinterpret_cast<float4*>(of)     = a;
  *reinterpret_cast<float4*>(of + 4) = b;
}

extern "C" void kernel_launch(void* const* d_in, const int* in_sizes, int n_in,
                              void* d_out, int out_size, void* d_ws, size_t ws_size,
                              hipStream_t stream) {
  const float* feat  = (const float*)d_in[0];
  const int*   eidx  = (const int*)d_in[1];
  const float* w1    = (const float*)d_in[2];
  const float* b1    = (const float*)d_in[3];
  const float* w2    = (const float*)d_in[4];
  const float* b2    = (const float*)d_in[5];
  const float* gamma = (const float*)d_in[6];
  const float* beta  = (const float*)d_in[7];
  float* out = (float*)d_out;

  const int nrows = in_sizes[0] / DD;       // 100000
  const int ne    = in_sizes[1] / 2;        // 400000
  const int nblk  = (nrows + TM - 1) / TM;  // 1563

  // ws layout (4B units):
  //  scsh[256] | ofs[nrows+1] | cur[nrows] | csr[ne] | bsum[SB] | bofs[SB] | stats[256] | cnt[nrows]
  float* scsh  = (float*)d_ws;
  int*   ofs   = (int*)d_ws + 256;
  int*   cur   = ofs + (nrows + 1);
  int*   csr   = cur + nrows;
  int*   bsum  = csr + ne;
  int*   bofs  = bsum + SB;
  float* stats = (float*)(bofs + SB);
  int*   cnt   = (int*)(stats + 256);
  // total ~2.8 MB

  // zero stats + cnt in one contiguous memset (graph-capture-safe)
  hipMemsetAsync(stats, 0, (256 + (size_t)nrows) * sizeof(float), stream);

  const long long total8 = (long long)nrows * DD / 8;   // 1.6M

  k_hist <<<(ne + 255) / 256,             256, 0, stream>>>(eidx, cnt, ne);
  k_scan1<<<SB,                           256, 0, stream>>>(cnt, bsum, nrows);
  k_scan2<<<1,                             SB, 0, stream>>>(bsum, bofs, ofs, nrows);
  k_scan3<<<SB,                           256, 0, stream>>>(cnt, bofs, ofs, cur, nrows);
  k_fill <<<(ne + 255) / 256,             256, 0, stream>>>(eidx, cur, csr, ne);
  k_mlp  <<<nblk,                         256, 0, stream>>>(feat, ofs, csr, w1, b1, w2, b2, out, stats, nrows);
  k_stats<<<1,                            128, 0, stream>>>(stats, gamma, beta, scsh, nrows);
  k_bn   <<<(int)((total8 + 255) / 256),  256, 0, stream>>>(out, scsh, total8);
}

// Round 7
// 295.630 us; speedup vs baseline: 5.3362x; 1.0309x over previous
//
#include <hip/hip_runtime.h>
#include <hip/hip_bf16.h>

#define DD 128
#define TM 64
#define LD 136   // padded LDS row stride (bf16 elems)
#define SB 128   // scan blocks

typedef short bf16x8 __attribute__((ext_vector_type(8)));
typedef float f32x4  __attribute__((ext_vector_type(4)));

__device__ __forceinline__ unsigned short f2bf(float f) {
  unsigned int u = __float_as_uint(f);
  u += 0x7FFFu + ((u >> 16) & 1u);   // RNE
  return (unsigned short)(u >> 16);
}
__device__ __forceinline__ unsigned int pack2(float lo, float hi) {
  return (unsigned int)f2bf(lo) | ((unsigned int)f2bf(hi) << 16);
}

// cnt[dst]++ per edge (int atomics on 400 KB — L2-resident)
__global__ __launch_bounds__(256) void k_hist(const int* __restrict__ ei, int* __restrict__ cnt,
                                              int ne) {
  int e = blockIdx.x * 256 + threadIdx.x;
  if (e < ne) atomicAdd(&cnt[ei[ne + e]], 1);
}

// ---- 3-stage parallel exclusive scan of cnt[0..n) -> ofs[0..n], cur = ofs ----
__global__ __launch_bounds__(256) void k_scan1(const int* __restrict__ cnt,
                                               int* __restrict__ bsum, int n) {
  __shared__ int red[256];
  int b = blockIdx.x, t = threadIdx.x;
  int chunk = (n + SB - 1) / SB;
  int lo = b * chunk, hi = min(n, lo + chunk);
  int s = 0;
  for (int i = lo + t; i < hi; i += 256) s += cnt[i];
  red[t] = s;
  __syncthreads();
  for (int off = 128; off; off >>= 1) {
    if (t < off) red[t] += red[t + off];
    __syncthreads();
  }
  if (t == 0) bsum[b] = red[0];
}

__global__ __launch_bounds__(SB) void k_scan2(const int* __restrict__ bsum,
                                              int* __restrict__ bofs,
                                              int* __restrict__ ofs, int n) {
  __shared__ int tmp[SB];
  int t = threadIdx.x;
  int mine = bsum[t];
  tmp[t] = mine;
  __syncthreads();
  for (int off = 1; off < SB; off <<= 1) {
    int v = (t >= off) ? tmp[t - off] : 0;
    __syncthreads();
    tmp[t] += v;
    __syncthreads();
  }
  bofs[t] = tmp[t] - mine;            // exclusive
  if (t == SB - 1) ofs[n] = tmp[t];   // total
}

__global__ __launch_bounds__(256) void k_scan3(const int* __restrict__ cnt,
                                               const int* __restrict__ bofs,
                                               int* __restrict__ ofs, int* __restrict__ cur,
                                               int n) {
  __shared__ int red[256];
  int b = blockIdx.x, t = threadIdx.x;
  int chunk  = (n + SB - 1) / SB;
  int tchunk = (chunk + 255) / 256;
  int blo = b * chunk, bhi = min(n, blo + chunk);
  int lo = blo + t * tchunk, hi = min(bhi, lo + tchunk);
  int s = 0;
  for (int i = lo; i < hi; ++i) s += cnt[i];
  int mine = s;
  red[t] = s;
  __syncthreads();
  for (int off = 1; off < 256; off <<= 1) {
    int v = (t >= off) ? red[t - off] : 0;
    __syncthreads();
    red[t] += v;
    __syncthreads();
  }
  int run = bofs[b] + red[t] - mine;
  for (int i = lo; i < hi; ++i) {
    int c = cnt[i];
    ofs[i] = run; cur[i] = run;
    run += c;
  }
}

// csr[pos] = src, pos = cur[dst]++
__global__ __launch_bounds__(256) void k_fill(const int* __restrict__ ei, int* __restrict__ cur,
                                              int* __restrict__ csr, int ne) {
  int e = blockIdx.x * 256 + threadIdx.x;
  if (e >= ne) return;
  int pos = atomicAdd(&cur[ei[ne + e]], 1);
  csr[pos] = ei[e];
}

// High-occupancy gather: hbuf[row] = bf16(feat[row] + sum_{s in csr} feat[s]).
// 16 threads/row, 8 cols each; ~25k waves -> latency hidden by TLP.
__global__ __launch_bounds__(256) void k_agg(const float* __restrict__ feat,
                                             const int* __restrict__ ofs,
                                             const int* __restrict__ csr,
                                             unsigned short* __restrict__ hbuf, int nrows) {
  int t = blockIdx.x * 256 + threadIdx.x;
  int row = t >> 4;
  if (row >= nrows) return;
  int c = (t & 15) << 3;
  const float* fr = feat + (long long)row * DD + c;
  float4 a = *reinterpret_cast<const float4*>(fr);
  float4 b = *reinterpret_cast<const float4*>(fr + 4);
  int o0 = ofs[row], o1 = ofs[row + 1];
  for (int j = o0; j < o1; ++j) {
    const float* fs = feat + (long long)csr[j] * DD + c;
    float4 x = *reinterpret_cast<const float4*>(fs);
    float4 y = *reinterpret_cast<const float4*>(fs + 4);
    a.x += x.x; a.y += x.y; a.z += x.z; a.w += x.w;
    b.x += y.x; b.y += y.y; b.z += y.z; b.w += y.w;
  }
  uint4 u;
  u.x = pack2(a.x, a.y); u.y = pack2(a.z, a.w);
  u.z = pack2(b.x, b.y); u.w = pack2(b.z, b.w);
  *reinterpret_cast<uint4*>(hbuf + (long long)row * DD + c) = u;
}

// Fused MLP via bf16 MFMA + BN stat atomics. GATHER=true folds the aggregation
// into staging (fallback when ws can't hold hbuf).
template <bool GATHER>
__global__ __launch_bounds__(256) void k_mlp(
    const float* __restrict__ feat, const int* __restrict__ ofs, const int* __restrict__ csr,
    const unsigned short* __restrict__ hbuf,
    const float* __restrict__ w1, const float* __restrict__ b1,
    const float* __restrict__ w2, const float* __restrict__ b2,
    float* __restrict__ out, float* __restrict__ stats, int nrows)
{
  __shared__ unsigned short ldsH[TM * LD];
  __shared__ unsigned short ldsH2[TM * LD];
  const int tid  = threadIdx.x;
  const int wave = tid >> 6, lane = tid & 63;
  const int q = lane >> 4, l16 = lane & 15;
  const int row0 = blockIdx.x * TM;
  const int col0 = wave * 32;

  // Weight B-frags (lane: n=lane&15, k=quad*8+j; B[k][n]=w[n][k]) + biases.
  bf16x8 bw1[2][4], bw2[2][4];
  float bias1[2], bias2[2];
  for (int n = 0; n < 2; ++n) {
    int jc = col0 + n * 16 + l16;
    bias1[n] = b1[jc];
    bias2[n] = b2[jc];
    for (int kk = 0; kk < 4; ++kk) {
      const float* p1 = w1 + jc * DD + kk * 32 + q * 8;
      const float* p2 = w2 + jc * DD + kk * 32 + q * 8;
      for (int j = 0; j < 8; ++j) {
        bw1[n][kk][j] = (short)f2bf(p1[j]);
        bw2[n][kk][j] = (short)f2bf(p2[j]);
      }
    }
  }

  // Stage h tile into LDS.
  for (int it = 0; it < 4; ++it) {
    int idx = it * 2048 + tid * 8;
    int r = idx >> 7, c = idx & 127;
    int row = row0 + r;
    uint4 u = make_uint4(0u, 0u, 0u, 0u);
    if (row < nrows) {
      if (GATHER) {
        const float* fr = feat + (long long)row * DD + c;
        float4 a = *reinterpret_cast<const float4*>(fr);
        float4 b = *reinterpret_cast<const float4*>(fr + 4);
        int o0 = ofs[row], o1 = ofs[row + 1];
        for (int j = o0; j < o1; ++j) {
          const float* fs = feat + (long long)csr[j] * DD + c;
          float4 x = *reinterpret_cast<const float4*>(fs);
          float4 y = *reinterpret_cast<const float4*>(fs + 4);
          a.x += x.x; a.y += x.y; a.z += x.z; a.w += x.w;
          b.x += y.x; b.y += y.y; b.z += y.z; b.w += y.w;
        }
        u.x = pack2(a.x, a.y); u.y = pack2(a.z, a.w);
        u.z = pack2(b.x, b.y); u.w = pack2(b.z, b.w);
      } else {
        u = *reinterpret_cast<const uint4*>(hbuf + (long long)row * DD + c);
      }
    }
    *reinterpret_cast<uint4*>(&ldsH[r * LD + c]) = u;
  }
  __syncthreads();

  f32x4 acc[4][2];
  const f32x4 zero = {0.f, 0.f, 0.f, 0.f};
  for (int m = 0; m < 4; ++m) for (int n = 0; n < 2; ++n) acc[m][n] = zero;

  // GEMM1 (A: m=lane&15, k=quad*8+j)
  for (int kk = 0; kk < 4; ++kk) {
    bf16x8 aF[4];
    for (int m = 0; m < 4; ++m)
      aF[m] = *reinterpret_cast<const bf16x8*>(&ldsH[(m * 16 + l16) * LD + kk * 32 + q * 8]);
    for (int m = 0; m < 4; ++m)
      for (int n = 0; n < 2; ++n)
        acc[m][n] = __builtin_amdgcn_mfma_f32_16x16x32_bf16(aF[m], bw1[n][kk], acc[m][n], 0, 0, 0);
  }

  // h2 = relu(acc + b1) -> LDS (C/D: col=lane&15, row=quad*4+reg)
  for (int m = 0; m < 4; ++m)
    for (int n = 0; n < 2; ++n)
      for (int r = 0; r < 4; ++r) {
        float v = fmaxf(acc[m][n][r] + bias1[n], 0.f);
        ldsH2[(m * 16 + q * 4 + r) * LD + (col0 + n * 16 + l16)] = f2bf(v);
      }
  __syncthreads();

  for (int m = 0; m < 4; ++m) for (int n = 0; n < 2; ++n) acc[m][n] = zero;

  // GEMM2
  for (int kk = 0; kk < 4; ++kk) {
    bf16x8 aF[4];
    for (int m = 0; m < 4; ++m)
      aF[m] = *reinterpret_cast<const bf16x8*>(&ldsH2[(m * 16 + l16) * LD + kk * 32 + q * 8]);
    for (int m = 0; m < 4; ++m)
      for (int n = 0; n < 2; ++n)
        acc[m][n] = __builtin_amdgcn_mfma_f32_16x16x32_bf16(aF[m], bw2[n][kk], acc[m][n], 0, 0, 0);
  }

  // Final relu, store pre-BN h (fp32), accumulate BN stats.
  float s[2] = {0.f, 0.f}, s2[2] = {0.f, 0.f};
  for (int m = 0; m < 4; ++m)
    for (int n = 0; n < 2; ++n) {
      int col = col0 + n * 16 + l16;
      for (int r = 0; r < 4; ++r) {
        int row = row0 + m * 16 + q * 4 + r;
        float v = fmaxf(acc[m][n][r] + bias2[n], 0.f);
        if (row < nrows) {
          out[(long long)row * DD + col] = v;
          s[n]  += v;
          s2[n] += v * v;
        }
      }
    }
  for (int off = 16; off < 64; off <<= 1)
    for (int n = 0; n < 2; ++n) {
      s[n]  += __shfl_xor(s[n], off);
      s2[n] += __shfl_xor(s2[n], off);
    }
  if (q == 0)
    for (int n = 0; n < 2; ++n) {
      int col = col0 + n * 16 + l16;
      atomicAdd(&stats[col],       s[n]);
      atomicAdd(&stats[128 + col], s2[n]);
    }
}

// stats -> scale/shift
__global__ __launch_bounds__(128) void k_stats(const float* __restrict__ stats,
                                               const float* __restrict__ gamma,
                                               const float* __restrict__ beta,
                                               float* __restrict__ scsh, int nrows) {
  int t = threadIdx.x;
  float mean = stats[t] / (float)nrows;
  float var  = fmaxf(stats[128 + t] / (float)nrows - mean * mean, 0.f);
  float inv  = rsqrtf(var + 1e-5f);
  float sc   = gamma[t] * inv;
  scsh[t]       = sc;
  scsh[128 + t] = beta[t] - mean * sc;
}

// In-place BN apply on out (fp32). One thread per 8 elems.
__global__ __launch_bounds__(256) void k_bn(float* __restrict__ out,
                                            const float* __restrict__ scsh,
                                            long long total8) {
  long long t = (long long)blockIdx.x * 256 + threadIdx.x;
  if (t >= total8) return;
  int c0 = (int)((t * 8) & 127);
  float4 sa = *reinterpret_cast<const float4*>(scsh + c0);
  float4 sb = *reinterpret_cast<const float4*>(scsh + c0 + 4);
  float4 ha = *reinterpret_cast<const float4*>(scsh + 128 + c0);
  float4 hb = *reinterpret_cast<const float4*>(scsh + 132 + c0);
  float* of = out + t * 8;
  float4 a = *reinterpret_cast<float4*>(of);
  float4 b = *reinterpret_cast<float4*>(of + 4);
  a.x = a.x * sa.x + ha.x; a.y = a.y * sa.y + ha.y;
  a.z = a.z * sa.z + ha.z; a.w = a.w * sa.w + ha.w;
  b.x = b.x * sb.x + hb.x; b.y = b.y * sb.y + hb.y;
  b.z = b.z * sb.z + hb.z; b.w = b.w * sb.w + hb.w;
  *reinterpret_cast<float4*>(of)     = a;
  *reinterpret_cast<float4*>(of + 4) = b;
}

extern "C" void kernel_launch(void* const* d_in, const int* in_sizes, int n_in,
                              void* d_out, int out_size, void* d_ws, size_t ws_size,
                              hipStream_t stream) {
  const float* feat  = (const float*)d_in[0];
  const int*   eidx  = (const int*)d_in[1];
  const float* w1    = (const float*)d_in[2];
  const float* b1    = (const float*)d_in[3];
  const float* w2    = (const float*)d_in[4];
  const float* b2    = (const float*)d_in[5];
  const float* gamma = (const float*)d_in[6];
  const float* beta  = (const float*)d_in[7];
  float* out = (float*)d_out;

  const int nrows = in_sizes[0] / DD;       // 100000
  const int ne    = in_sizes[1] / 2;        // 400000
  const int nblk  = (nrows + TM - 1) / TM;  // 1563

  // hbuf (bf16 h) optionally at ws start; small tables after it.
  const size_t hbuf_bytes  = (size_t)nrows * DD * sizeof(unsigned short);   // 25.6 MB
  const size_t small_words = 256 + (size_t)(nrows + 1) + nrows + ne + SB + SB + 256 + nrows;
  const bool   split       = ws_size >= hbuf_bytes + small_words * 4;

  unsigned short* hbuf = (unsigned short*)d_ws;
  int* base = (int*)((char*)d_ws + (split ? hbuf_bytes : 0));

  float* scsh  = (float*)base;
  int*   ofs   = base + 256;
  int*   cur   = ofs + (nrows + 1);
  int*   csr   = cur + nrows;
  int*   bsum  = csr + ne;
  int*   bofs  = bsum + SB;
  float* stats = (float*)(bofs + SB);
  int*   cnt   = (int*)(stats + 256);

  hipMemsetAsync(stats, 0, (256 + (size_t)nrows) * sizeof(float), stream);

  const long long total8 = (long long)nrows * DD / 8;   // 1.6M

  k_hist <<<(ne + 255) / 256,             256, 0, stream>>>(eidx, cnt, ne);
  k_scan1<<<SB,                           256, 0, stream>>>(cnt, bsum, nrows);
  k_scan2<<<1,                             SB, 0, stream>>>(bsum, bofs, ofs, nrows);
  k_scan3<<<SB,                           256, 0, stream>>>(cnt, bofs, ofs, cur, nrows);
  k_fill <<<(ne + 255) / 256,             256, 0, stream>>>(eidx, cur, csr, ne);
  if (split) {
    k_agg        <<<(nrows * 16 + 255) / 256, 256, 0, stream>>>(feat, ofs, csr, hbuf, nrows);
    k_mlp<false> <<<nblk,                     256, 0, stream>>>(feat, ofs, csr, hbuf, w1, b1, w2, b2, out, stats, nrows);
  } else {
    k_mlp<true>  <<<nblk,                     256, 0, stream>>>(feat, ofs, csr, hbuf, w1, b1, w2, b2, out, stats, nrows);
  }
  k_stats<<<1,                            128, 0, stream>>>(stats, gamma, beta, scsh, nrows);
  k_bn   <<<(int)((total8 + 255) / 256),  256, 0, stream>>>(out, scsh, total8);
}

// Round 8
// 294.707 us; speedup vs baseline: 5.3529x; 1.0031x over previous
//
#include <hip/hip_runtime.h>
#include <hip/hip_bf16.h>

#define DD 128
#define TM 64
#define LD 136        // padded LDS row stride (bf16 elems)
#define SB 128        // scan blocks
#define GRID_MLP 1024 // 4 blocks/CU persistent

typedef short bf16x8 __attribute__((ext_vector_type(8)));
typedef float f32x4  __attribute__((ext_vector_type(4)));

__device__ __forceinline__ unsigned short f2bf(float f) {
  unsigned int u = __float_as_uint(f);
  u += 0x7FFFu + ((u >> 16) & 1u);   // RNE
  return (unsigned short)(u >> 16);
}
__device__ __forceinline__ unsigned int pack2(float lo, float hi) {
  return (unsigned int)f2bf(lo) | ((unsigned int)f2bf(hi) << 16);
}
__device__ __forceinline__ float bf2f(unsigned short u) {
  union { unsigned int i; float f; } x; x.i = ((unsigned int)u) << 16; return x.f;
}

// One-time fp32 -> bf16 weight conversion (64 KB total, L2-resident afterwards)
__global__ __launch_bounds__(256) void k_prep(const float* __restrict__ w1,
                                              const float* __restrict__ w2,
                                              unsigned short* __restrict__ wbf1,
                                              unsigned short* __restrict__ wbf2) {
  int i = blockIdx.x * 256 + threadIdx.x;
  if (i < DD * DD) {
    wbf1[i] = f2bf(w1[i]);
    wbf2[i] = f2bf(w2[i]);
  }
}

// cnt[dst]++ per edge (int atomics, L2-resident)
__global__ __launch_bounds__(256) void k_hist(const int* __restrict__ ei, int* __restrict__ cnt,
                                              int ne) {
  int e = blockIdx.x * 256 + threadIdx.x;
  if (e < ne) atomicAdd(&cnt[ei[ne + e]], 1);
}

// ---- 3-stage parallel exclusive scan of cnt[0..n) -> ofs[0..n], cur = ofs ----
__global__ __launch_bounds__(256) void k_scan1(const int* __restrict__ cnt,
                                               int* __restrict__ bsum, int n) {
  __shared__ int red[256];
  int b = blockIdx.x, t = threadIdx.x;
  int chunk = (n + SB - 1) / SB;
  int lo = b * chunk, hi = min(n, lo + chunk);
  int s = 0;
  for (int i = lo + t; i < hi; i += 256) s += cnt[i];
  red[t] = s;
  __syncthreads();
  for (int off = 128; off; off >>= 1) {
    if (t < off) red[t] += red[t + off];
    __syncthreads();
  }
  if (t == 0) bsum[b] = red[0];
}

__global__ __launch_bounds__(SB) void k_scan2(const int* __restrict__ bsum,
                                              int* __restrict__ bofs,
                                              int* __restrict__ ofs, int n) {
  __shared__ int tmp[SB];
  int t = threadIdx.x;
  int mine = bsum[t];
  tmp[t] = mine;
  __syncthreads();
  for (int off = 1; off < SB; off <<= 1) {
    int v = (t >= off) ? tmp[t - off] : 0;
    __syncthreads();
    tmp[t] += v;
    __syncthreads();
  }
  bofs[t] = tmp[t] - mine;
  if (t == SB - 1) ofs[n] = tmp[t];
}

__global__ __launch_bounds__(256) void k_scan3(const int* __restrict__ cnt,
                                               const int* __restrict__ bofs,
                                               int* __restrict__ ofs, int* __restrict__ cur,
                                               int n) {
  __shared__ int red[256];
  int b = blockIdx.x, t = threadIdx.x;
  int chunk  = (n + SB - 1) / SB;
  int tchunk = (chunk + 255) / 256;
  int blo = b * chunk, bhi = min(n, blo + chunk);
  int lo = blo + t * tchunk, hi = min(bhi, lo + tchunk);
  int s = 0;
  for (int i = lo; i < hi; ++i) s += cnt[i];
  int mine = s;
  red[t] = s;
  __syncthreads();
  for (int off = 1; off < 256; off <<= 1) {
    int v = (t >= off) ? red[t - off] : 0;
    __syncthreads();
    red[t] += v;
    __syncthreads();
  }
  int run = bofs[b] + red[t] - mine;
  for (int i = lo; i < hi; ++i) {
    int c = cnt[i];
    ofs[i] = run; cur[i] = run;
    run += c;
  }
}

// csr[pos] = src, pos = cur[dst]++
__global__ __launch_bounds__(256) void k_fill(const int* __restrict__ ei, int* __restrict__ cur,
                                              int* __restrict__ csr, int ne) {
  int e = blockIdx.x * 256 + threadIdx.x;
  if (e >= ne) return;
  int pos = atomicAdd(&cur[ei[ne + e]], 1);
  csr[pos] = ei[e];
}

// Persistent fused kernel: per 64-row tile — gather-aggregate, 2-layer MLP via
// bf16 MFMA, vectorized bf16 epilogue to hbuf, BN stat atomics.
__global__ __launch_bounds__(256) void k_mlp(
    const float* __restrict__ feat, const int* __restrict__ ofs, const int* __restrict__ csr,
    const unsigned short* __restrict__ wbf1, const float* __restrict__ b1,
    const unsigned short* __restrict__ wbf2, const float* __restrict__ b2,
    unsigned short* __restrict__ hbuf, float* __restrict__ stats, int nrows, int ntiles)
{
  __shared__ unsigned short ldsH[TM * LD];
  __shared__ unsigned short ldsH2[TM * LD];
  const int tid  = threadIdx.x;
  const int wave = tid >> 6, lane = tid & 63;
  const int q = lane >> 4, l16 = lane & 15;
  const int col0 = wave * 32;

  // Weight fragments as 16B vector loads from L2-resident bf16 arrays.
  bf16x8 bw1[2][4], bw2[2][4];
  float bias1[2], bias2[2];
  for (int n = 0; n < 2; ++n) {
    int jc = col0 + n * 16 + l16;
    bias1[n] = b1[jc];
    bias2[n] = b2[jc];
    for (int kk = 0; kk < 4; ++kk) {
      bw1[n][kk] = *reinterpret_cast<const bf16x8*>(wbf1 + jc * DD + kk * 32 + q * 8);
      bw2[n][kk] = *reinterpret_cast<const bf16x8*>(wbf2 + jc * DD + kk * 32 + q * 8);
    }
  }

  for (int tile = blockIdx.x; tile < ntiles; tile += GRID_MLP) {
    const int row0 = tile * TM;

    // Stage: h = feat[row] + sum(neighbors) -> bf16 LDS. 16 thr/row, 8 cols each.
    for (int it = 0; it < 4; ++it) {
      int idx = it * 2048 + tid * 8;
      int r = idx >> 7, c = idx & 127;
      int row = row0 + r;
      uint4 u = make_uint4(0u, 0u, 0u, 0u);
      if (row < nrows) {
        const float* fr = feat + (long long)row * DD + c;
        float4 a = *reinterpret_cast<const float4*>(fr);
        float4 b = *reinterpret_cast<const float4*>(fr + 4);
        int o0 = ofs[row], o1 = ofs[row + 1];
        for (int j = o0; j < o1; ++j) {
          const float* fs = feat + (long long)csr[j] * DD + c;
          float4 x = *reinterpret_cast<const float4*>(fs);
          float4 y = *reinterpret_cast<const float4*>(fs + 4);
          a.x += x.x; a.y += x.y; a.z += x.z; a.w += x.w;
          b.x += y.x; b.y += y.y; b.z += y.z; b.w += y.w;
        }
        u.x = pack2(a.x, a.y); u.y = pack2(a.z, a.w);
        u.z = pack2(b.x, b.y); u.w = pack2(b.z, b.w);
      }
      *reinterpret_cast<uint4*>(&ldsH[r * LD + c]) = u;
    }
    __syncthreads();

    f32x4 acc[4][2];
    const f32x4 zero = {0.f, 0.f, 0.f, 0.f};
    for (int m = 0; m < 4; ++m) for (int n = 0; n < 2; ++n) acc[m][n] = zero;

    // GEMM1 (A: m=lane&15, k=quad*8+j)
    for (int kk = 0; kk < 4; ++kk) {
      bf16x8 aF[4];
      for (int m = 0; m < 4; ++m)
        aF[m] = *reinterpret_cast<const bf16x8*>(&ldsH[(m * 16 + l16) * LD + kk * 32 + q * 8]);
      for (int m = 0; m < 4; ++m)
        for (int n = 0; n < 2; ++n)
          acc[m][n] = __builtin_amdgcn_mfma_f32_16x16x32_bf16(aF[m], bw1[n][kk], acc[m][n], 0, 0, 0);
    }

    // h2 = relu(acc + b1) -> LDS (C/D: col=lane&15, row=quad*4+reg)
    for (int m = 0; m < 4; ++m)
      for (int n = 0; n < 2; ++n)
        for (int r = 0; r < 4; ++r) {
          float v = fmaxf(acc[m][n][r] + bias1[n], 0.f);
          ldsH2[(m * 16 + q * 4 + r) * LD + (col0 + n * 16 + l16)] = f2bf(v);
        }
    __syncthreads();

    for (int m = 0; m < 4; ++m) for (int n = 0; n < 2; ++n) acc[m][n] = zero;

    // GEMM2
    for (int kk = 0; kk < 4; ++kk) {
      bf16x8 aF[4];
      for (int m = 0; m < 4; ++m)
        aF[m] = *reinterpret_cast<const bf16x8*>(&ldsH2[(m * 16 + l16) * LD + kk * 32 + q * 8]);
      for (int m = 0; m < 4; ++m)
        for (int n = 0; n < 2; ++n)
          acc[m][n] = __builtin_amdgcn_mfma_f32_16x16x32_bf16(aF[m], bw2[n][kk], acc[m][n], 0, 0, 0);
    }

    // Epilogue: relu+bias, BN stats from fp32, pack bf16 into ldsH (reuse).
    float s[2] = {0.f, 0.f}, s2[2] = {0.f, 0.f};
    for (int m = 0; m < 4; ++m)
      for (int n = 0; n < 2; ++n) {
        int col = col0 + n * 16 + l16;
        for (int r = 0; r < 4; ++r) {
          int rl = m * 16 + q * 4 + r;
          float v = fmaxf(acc[m][n][r] + bias2[n], 0.f);
          ldsH[rl * LD + col] = f2bf(v);
          if (row0 + rl < nrows) { s[n] += v; s2[n] += v * v; }
        }
      }
    for (int off = 16; off < 64; off <<= 1)
      for (int n = 0; n < 2; ++n) {
        s[n]  += __shfl_xor(s[n], off);
        s2[n] += __shfl_xor(s2[n], off);
      }
    if (q == 0)
      for (int n = 0; n < 2; ++n) {
        int col = col0 + n * 16 + l16;
        atomicAdd(&stats[col],       s[n]);
        atomicAdd(&stats[128 + col], s2[n]);
      }
    __syncthreads();

    // Coalesced bf16 store of the tile to hbuf.
    for (int it = 0; it < 4; ++it) {
      int idx = it * 2048 + tid * 8;
      int r = idx >> 7, c = idx & 127;
      int row = row0 + r;
      if (row < nrows)
        *reinterpret_cast<uint4*>(hbuf + (long long)row * DD + c) =
            *reinterpret_cast<const uint4*>(&ldsH[r * LD + c]);
    }
    __syncthreads();  // protect ldsH before next tile's staging
  }
}

// stats -> scale/shift
__global__ __launch_bounds__(128) void k_stats(const float* __restrict__ stats,
                                               const float* __restrict__ gamma,
                                               const float* __restrict__ beta,
                                               float* __restrict__ scsh, int nrows) {
  int t = threadIdx.x;
  float mean = stats[t] / (float)nrows;
  float var  = fmaxf(stats[128 + t] / (float)nrows - mean * mean, 0.f);
  float inv  = rsqrtf(var + 1e-5f);
  float sc   = gamma[t] * inv;
  scsh[t]       = sc;
  scsh[128 + t] = beta[t] - mean * sc;
}

// BN apply: read bf16 hbuf (L3-warm), write fp32 out. One thread per 8 elems.
__global__ __launch_bounds__(256) void k_bn(const unsigned short* __restrict__ hbuf,
                                            float* __restrict__ out,
                                            const float* __restrict__ scsh,
                                            long long total8) {
  long long t = (long long)blockIdx.x * 256 + threadIdx.x;
  if (t >= total8) return;
  int c0 = (int)((t * 8) & 127);
  float4 sa = *reinterpret_cast<const float4*>(scsh + c0);
  float4 sb = *reinterpret_cast<const float4*>(scsh + c0 + 4);
  float4 ha = *reinterpret_cast<const float4*>(scsh + 128 + c0);
  float4 hb = *reinterpret_cast<const float4*>(scsh + 132 + c0);
  uint4 u = *reinterpret_cast<const uint4*>(hbuf + t * 8);
  float4 a, b;
  a.x = bf2f((unsigned short)(u.x & 0xFFFF)) * sa.x + ha.x;
  a.y = bf2f((unsigned short)(u.x >> 16))    * sa.y + ha.y;
  a.z = bf2f((unsigned short)(u.y & 0xFFFF)) * sa.z + ha.z;
  a.w = bf2f((unsigned short)(u.y >> 16))    * sa.w + ha.w;
  b.x = bf2f((unsigned short)(u.z & 0xFFFF)) * sb.x + hb.x;
  b.y = bf2f((unsigned short)(u.z >> 16))    * sb.y + hb.y;
  b.z = bf2f((unsigned short)(u.w & 0xFFFF)) * sb.z + hb.z;
  b.w = bf2f((unsigned short)(u.w >> 16))    * sb.w + hb.w;
  float* of = out + t * 8;
  *reinterpret_cast<float4*>(of)     = a;
  *reinterpret_cast<float4*>(of + 4) = b;
}

extern "C" void kernel_launch(void* const* d_in, const int* in_sizes, int n_in,
                              void* d_out, int out_size, void* d_ws, size_t ws_size,
                              hipStream_t stream) {
  const float* feat  = (const float*)d_in[0];
  const int*   eidx  = (const int*)d_in[1];
  const float* w1    = (const float*)d_in[2];
  const float* b1    = (const float*)d_in[3];
  const float* w2    = (const float*)d_in[4];
  const float* b2    = (const float*)d_in[5];
  const float* gamma = (const float*)d_in[6];
  const float* beta  = (const float*)d_in[7];
  float* out = (float*)d_out;

  const int nrows  = in_sizes[0] / DD;       // 100000
  const int ne     = in_sizes[1] / 2;        // 400000
  const int ntiles = (nrows + TM - 1) / TM;  // 1563

  // ws layout (4B words), hbuf last (16B-aligned by construction):
  int* base = (int*)d_ws;
  unsigned short* wbf1 = (unsigned short*)base;            // 8192 words
  unsigned short* wbf2 = (unsigned short*)(base + 8192);   // 8192 words
  float* scsh  = (float*)(base + 16384);                   // 256
  int*   ofs   = base + 16384 + 256;                       // nrows+1
  int*   cur   = ofs + (nrows + 1);
  int*   csr   = cur + nrows;
  int*   bsum  = csr + ne;
  int*   bofs  = bsum + SB;
  float* stats = (float*)(bofs + SB);                      // 256
  int*   cnt   = (int*)(stats + 256);                      // nrows
  long long w_off = (long long)(cnt + nrows - base);
  w_off = (w_off + 3) & ~3LL;                              // 16B align
  unsigned short* hbuf = (unsigned short*)(base + w_off);  // nrows*DD bf16 (25.6 MB)

  hipMemsetAsync(stats, 0, (256 + (size_t)nrows) * sizeof(float), stream);

  const long long total8 = (long long)nrows * DD / 8;      // 1.6M

  k_prep <<<(DD * DD + 255) / 256,        256, 0, stream>>>(w1, w2, wbf1, wbf2);
  k_hist <<<(ne + 255) / 256,             256, 0, stream>>>(eidx, cnt, ne);
  k_scan1<<<SB,                           256, 0, stream>>>(cnt, bsum, nrows);
  k_scan2<<<1,                             SB, 0, stream>>>(bsum, bofs, ofs, nrows);
  k_scan3<<<SB,                           256, 0, stream>>>(cnt, bofs, ofs, cur, nrows);
  k_fill <<<(ne + 255) / 256,             256, 0, stream>>>(eidx, cur, csr, ne);
  k_mlp  <<<GRID_MLP,                     256, 0, stream>>>(feat, ofs, csr, wbf1, b1, wbf2, b2,
                                                            hbuf, stats, nrows, ntiles);
  k_stats<<<1,                            128, 0, stream>>>(stats, gamma, beta, scsh, nrows);
  k_bn   <<<(int)((total8 + 255) / 256),  256, 0, stream>>>(hbuf, out, scsh, total8);
}